// Round 1
// baseline (72.202 us; speedup 1.0000x reference)
//
#include <hip/hip_runtime.h>
#include <hip/hip_bf16.h>

typedef __bf16 bf16x8 __attribute__((ext_vector_type(8)));
typedef __bf16 bf16x2 __attribute__((ext_vector_type(2)));
typedef float f32x4 __attribute__((ext_vector_type(4)));

#define GLOBAL_AS(p) ((const __attribute__((address_space(1))) void*)(p))
#define LDS_AS(p)    ((__attribute__((address_space(3))) void*)(p))

#define LP 8192
#define D 128
#define EPS 1e-6f
#define TWOEPS 2e-6f
#define CEPS 1.28e-10f   /* 128 * EPS^2 */
#define MARGIN 0.2f

// ---------------- Phase A1: normalize n[0], store nhat (f32) + {qn, sn} ----------------
__global__ void norm_n_kernel(const float* __restrict__ n, float* __restrict__ nhat,
                              float* __restrict__ nstats) {
    int lane = threadIdx.x;  // 64 threads
    float2 x = ((const float2*)n)[lane];  // row 0 = first 128 floats
    float ss = x.x * x.x + x.y * x.y;
#pragma unroll
    for (int m = 1; m < 64; m <<= 1) ss += __shfl_xor(ss, m);
    float inv = 1.0f / fmaxf(sqrtf(ss), 1e-12f);
    float a0 = x.x * inv, a1 = x.y * inv;
    nhat[2 * lane] = a0;
    nhat[2 * lane + 1] = a1;
    float s = a0 + a1;
    float q = a0 * a0 + a1 * a1;
#pragma unroll
    for (int m = 1; m < 64; m <<= 1) { s += __shfl_xor(s, m); q += __shfl_xor(q, m); }
    if (lane == 0) { nstats[0] = q; nstats[1] = s; }
}

// ---------------- Phase A2: normalize p rows -> bf16, compute u/v/w ----------------
// u[i] = q_i + 2*EPS*s_i ; v[i] = q_i - 2*EPS*s_i ; w[i] = MARGIN - d_pn(i)
__global__ __launch_bounds__(256) void rows_kernel(const float* __restrict__ p,
                                                   const float* __restrict__ nhat,
                                                   const float* __restrict__ nstats,
                                                   __bf16* __restrict__ pb,
                                                   float* __restrict__ u,
                                                   float* __restrict__ v,
                                                   float* __restrict__ w) {
    int tid = threadIdx.x;
    int wave = tid >> 6, lane = tid & 63;
    int row = blockIdx.x * 4 + wave;
    const float2* pr = (const float2*)(p + (size_t)row * D);
    float2 x = pr[lane];
    float ss = fmaf(x.x, x.x, x.y * x.y);
#pragma unroll
    for (int m = 1; m < 64; m <<= 1) ss += __shfl_xor(ss, m);
    float inv = 1.0f / fmaxf(sqrtf(ss), 1e-12f);
    float a0 = x.x * inv, a1 = x.y * inv;

    bf16x2 hv;
    hv[0] = (__bf16)a0;
    hv[1] = (__bf16)a1;
    *(bf16x2*)(pb + (size_t)row * D + 2 * lane) = hv;

    float2 nh = ((const float2*)nhat)[lane];
    float s = a0 + a1;
    float q = fmaf(a0, a0, a1 * a1);
    float dn = fmaf(a0, nh.x, a1 * nh.y);
#pragma unroll
    for (int m = 1; m < 64; m <<= 1) {
        s += __shfl_xor(s, m);
        q += __shfl_xor(q, m);
        dn += __shfl_xor(dn, m);
    }
    if (lane == 0) {
        float qn = nstats[0], sn = nstats[1];
        float sq = q + qn - 2.0f * dn + TWOEPS * (s - sn) + CEPS;
        float dpn = sqrtf(fmaxf(sq, 0.0f));
        u[row] = q + TWOEPS * s;
        v[row] = q - TWOEPS * s;
        w[row] = MARGIN - dpn;
    }
}

// ---------------- Phase B: 128x128-tile pairwise distance + fused epilogue ----------------
__global__ __launch_bounds__(256) void pair_kernel(const __bf16* __restrict__ pb,
                                                   const float* __restrict__ u,
                                                   const float* __restrict__ v,
                                                   const float* __restrict__ w,
                                                   float* __restrict__ partials) {
    __shared__ __align__(16) char smem[65536];  // lA 32KB | lB 32KB ; reused for reduce
    char* lAc = smem;
    char* lBc = smem + 32768;

    const int tid = threadIdx.x;
    const int wave = tid >> 6, lane = tid & 63;
    const int i0 = blockIdx.y * 128, j0 = blockIdx.x * 128;

    const char* gA = (const char*)(pb + (size_t)i0 * D);  // 256 B per row, rows contiguous
    const char* gB = (const char*)(pb + (size_t)j0 * D);

    // Stage both 32KB tiles. LDS layout = swizzled: linear dest, inverse-swizzled source.
    // swz(o) = o ^ ((row(o)&7)<<4), row(o) = o>>8 (256B rows). XOR only touches bits 4..6.
#pragma unroll
    for (int r = 0; r < 8; ++r) {
        int obase = r * 4096 + wave * 1024;  // wave-uniform LDS base
        int o = obase + lane * 16;           // this lane's linear LDS byte offset
        int src = o ^ (((o >> 8) & 7) << 4);
        __builtin_amdgcn_global_load_lds(GLOBAL_AS(gA + src), LDS_AS(lAc + obase), 16, 0, 0);
        __builtin_amdgcn_global_load_lds(GLOBAL_AS(gB + src), LDS_AS(lBc + obase), 16, 0, 0);
    }
    __syncthreads();

    const int wr = wave >> 1, wc = wave & 1;  // 2x2 waves, each owns 64x64 output
    const int fr = lane & 15;                 // fragment row (A) / col (B)
    const int kg = lane >> 4;                 // k-group 0..3

    f32x4 acc[4][4] = {};

#pragma unroll
    for (int ks = 0; ks < 4; ++ks) {
        const int kbyte = ks * 64 + kg * 16;
        bf16x8 afr[4], bfr[4];
#pragma unroll
        for (int mt = 0; mt < 4; ++mt) {
            int row = wr * 64 + mt * 16 + fr;
            int off = (row * 256 + kbyte) ^ ((row & 7) << 4);
            afr[mt] = *(const bf16x8*)(lAc + off);
        }
#pragma unroll
        for (int nt = 0; nt < 4; ++nt) {
            int row = wc * 64 + nt * 16 + fr;
            int off = (row * 256 + kbyte) ^ ((row & 7) << 4);
            bfr[nt] = *(const bf16x8*)(lBc + off);
        }
#pragma unroll
        for (int mt = 0; mt < 4; ++mt)
#pragma unroll
            for (int nt = 0; nt < 4; ++nt)
                acc[mt][nt] = __builtin_amdgcn_mfma_f32_16x16x32_bf16(afr[mt], bfr[nt],
                                                                      acc[mt][nt], 0, 0, 0);
    }

    // Epilogue: C/D layout (16x16x32): col = lane&15, row = (lane>>4)*4 + reg
    float uu[16], ww[16], vv[4];
#pragma unroll
    for (int mt = 0; mt < 4; ++mt)
#pragma unroll
        for (int r2 = 0; r2 < 4; ++r2) {
            int i = i0 + wr * 64 + mt * 16 + kg * 4 + r2;
            uu[mt * 4 + r2] = u[i] + CEPS;
            ww[mt * 4 + r2] = w[i];
        }
#pragma unroll
    for (int nt = 0; nt < 4; ++nt) vv[nt] = v[j0 + wc * 64 + nt * 16 + fr];

    float local = 0.0f;
#pragma unroll
    for (int mt = 0; mt < 4; ++mt)
#pragma unroll
        for (int nt = 0; nt < 4; ++nt)
#pragma unroll
            for (int r2 = 0; r2 < 4; ++r2) {
                float dot = acc[mt][nt][r2];
                float sq = fmaf(-2.0f, dot, uu[mt * 4 + r2] + vv[nt]);
                float dpp = sqrtf(fmaxf(sq, 0.0f));
                local += fmaxf(dpp + ww[mt * 4 + r2], 0.0f);
            }

    // block reduction (deterministic)
#pragma unroll
    for (int m = 1; m < 64; m <<= 1) local += __shfl_xor(local, m);
    __syncthreads();  // everyone done with lA/lB before reuse
    float* sred = (float*)smem;
    if (lane == 0) sred[wave] = local;
    __syncthreads();
    if (tid == 0)
        partials[blockIdx.y * gridDim.x + blockIdx.x] = sred[0] + sred[1] + sred[2] + sred[3];
}

// ---------------- Phase C: final reduce ----------------
__global__ void reduce_kernel(const float* __restrict__ partials, float* __restrict__ out,
                              int npart) {
    __shared__ float sred[4];
    float s = 0.0f;
    for (int t = threadIdx.x; t < npart; t += 256) s += partials[t];
#pragma unroll
    for (int m = 1; m < 64; m <<= 1) s += __shfl_xor(s, m);
    int wave = threadIdx.x >> 6, lane = threadIdx.x & 63;
    if (lane == 0) sred[wave] = s;
    __syncthreads();
    if (threadIdx.x == 0) {
        float tot = sred[0] + sred[1] + sred[2] + sred[3];
        float loss = tot * (1.0f / 67100672.0f);  // (8192*8191) exact in fp32
        out[0] = fmaxf(loss, 0.0f);
    }
}

extern "C" void kernel_launch(void* const* d_in, const int* in_sizes, int n_in,
                              void* d_out, int out_size, void* d_ws, size_t ws_size,
                              hipStream_t stream) {
    const float* p = (const float*)d_in[0];  // [8192,128] f32
    const float* n = (const float*)d_in[1];  // [64,128] f32
    float* out = (float*)d_out;
    char* ws = (char*)d_ws;

    // ws layout
    __bf16* pb     = (__bf16*)ws;                              // 2 MB
    float*  u      = (float*)(ws + (2u << 20));                // 32 KB
    float*  v      = (float*)(ws + (2u << 20) + (32u << 10));  // 32 KB
    float*  w      = (float*)(ws + (2u << 20) + (64u << 10));  // 32 KB
    float*  nhat   = (float*)(ws + (2u << 20) + (96u << 10));  // 512 B
    float*  nstats = nhat + 128;                               // 8 B
    float*  parts  = (float*)(ws + (2u << 20) + (100u << 10)); // 16 KB

    hipLaunchKernelGGL(norm_n_kernel, dim3(1), dim3(64), 0, stream, n, nhat, nstats);
    hipLaunchKernelGGL(rows_kernel, dim3(LP / 4), dim3(256), 0, stream, p, nhat, nstats,
                       pb, u, v, w);
    hipLaunchKernelGGL(pair_kernel, dim3(64, 64), dim3(256), 0, stream, pb, u, v, w, parts);
    hipLaunchKernelGGL(reduce_kernel, dim3(1), dim3(256), 0, stream, parts, out, 64 * 64);
}

// Round 2
// 46.152 us; speedup vs baseline: 1.5644x; 1.5644x over previous
//
#include <hip/hip_runtime.h>
#include <hip/hip_bf16.h>

typedef __bf16 bf16x8 __attribute__((ext_vector_type(8)));
typedef __bf16 bf16x2 __attribute__((ext_vector_type(2)));
typedef float f32x4 __attribute__((ext_vector_type(4)));

#define GLOBAL_AS(p) ((const __attribute__((address_space(1))) void*)(p))
#define LDS_AS(p)    ((__attribute__((address_space(3))) void*)(p))

#define LP 8192
#define D 128
#define EPS 1e-6f
#define TWOEPS 2e-6f
#define CEPS 1.28e-10f   /* 128 * EPS^2 */
#define MARGIN 0.2f
#define NTILE 64         /* 8192/128 */
#define NTRI 2080        /* 64*65/2 lower-triangular tiles */

// ---------------- Phase A1: normalize n[0], store nhat (f32) + {qn, sn} ----------------
__global__ void norm_n_kernel(const float* __restrict__ n, float* __restrict__ nhat,
                              float* __restrict__ nstats) {
    int lane = threadIdx.x;  // 64 threads
    float2 x = ((const float2*)n)[lane];  // row 0 = first 128 floats
    float ss = x.x * x.x + x.y * x.y;
#pragma unroll
    for (int m = 1; m < 64; m <<= 1) ss += __shfl_xor(ss, m);
    float inv = 1.0f / fmaxf(__builtin_amdgcn_sqrtf(ss), 1e-12f);
    float a0 = x.x * inv, a1 = x.y * inv;
    nhat[2 * lane] = a0;
    nhat[2 * lane + 1] = a1;
    float s = a0 + a1;
    float q = a0 * a0 + a1 * a1;
#pragma unroll
    for (int m = 1; m < 64; m <<= 1) { s += __shfl_xor(s, m); q += __shfl_xor(q, m); }
    if (lane == 0) { nstats[0] = q; nstats[1] = s; }
}

// ---------------- Phase A2: normalize p rows -> bf16, compute u/v/w ----------------
// u[i] = q_i + 2*EPS*s_i ; v[i] = q_i - 2*EPS*s_i ; w[i] = MARGIN - d_pn(i)
__global__ __launch_bounds__(256) void rows_kernel(const float* __restrict__ p,
                                                   const float* __restrict__ nhat,
                                                   const float* __restrict__ nstats,
                                                   __bf16* __restrict__ pb,
                                                   float* __restrict__ u,
                                                   float* __restrict__ v,
                                                   float* __restrict__ w) {
    int tid = threadIdx.x;
    int wave = tid >> 6, lane = tid & 63;
    int row = blockIdx.x * 4 + wave;
    const float2* pr = (const float2*)(p + (size_t)row * D);
    float2 x = pr[lane];
    float ss = fmaf(x.x, x.x, x.y * x.y);
#pragma unroll
    for (int m = 1; m < 64; m <<= 1) ss += __shfl_xor(ss, m);
    // keep precise sqrt semantics for normalization (matches reference closely;
    // cost negligible here)
    float inv = 1.0f / fmaxf(sqrtf(ss), 1e-12f);
    float a0 = x.x * inv, a1 = x.y * inv;

    bf16x2 hv;
    hv[0] = (__bf16)a0;
    hv[1] = (__bf16)a1;
    *(bf16x2*)(pb + (size_t)row * D + 2 * lane) = hv;

    float2 nh = ((const float2*)nhat)[lane];
    float s = a0 + a1;
    float q = fmaf(a0, a0, a1 * a1);
    float dn = fmaf(a0, nh.x, a1 * nh.y);
#pragma unroll
    for (int m = 1; m < 64; m <<= 1) {
        s += __shfl_xor(s, m);
        q += __shfl_xor(q, m);
        dn += __shfl_xor(dn, m);
    }
    if (lane == 0) {
        float qn = nstats[0], sn = nstats[1];
        float sq = q + qn - 2.0f * dn + TWOEPS * (s - sn) + CEPS;
        float dpn = sqrtf(fmaxf(sq, 0.0f));
        u[row] = q + TWOEPS * s;
        v[row] = q - TWOEPS * s;
        w[row] = MARGIN - dpn;
    }
}

// ---------------- Phase B: triangular 128x128-tile pair kernel ----------------
// For tile (ti >= tj): dots computed once; off-diagonal tiles emit both
// term(i,j) and term(j,i) from the same dot. Diagonal tiles emit single terms
// over the full 128x128 (they are their own mirror).
__global__ __launch_bounds__(256) void pair_kernel(const __bf16* __restrict__ pb,
                                                   const float* __restrict__ u,
                                                   const float* __restrict__ v,
                                                   const float* __restrict__ w,
                                                   float* __restrict__ partials) {
    __shared__ __align__(16) char smem[65536];  // lA 32KB | lB 32KB
    char* lAc = smem;

    // triangular decode: b = ti*(ti+1)/2 + tj, tj <= ti
    const int b = blockIdx.x;
    int ti = (int)((__builtin_amdgcn_sqrtf(8.0f * (float)b + 1.0f) - 1.0f) * 0.5f);
    while ((ti + 1) * (ti + 2) / 2 <= b) ++ti;
    while (ti * (ti + 1) / 2 > b) --ti;
    const int tj = b - ti * (ti + 1) / 2;
    const bool diag = (ti == tj);

    char* lBc = diag ? lAc : (smem + 32768);

    const int tid = threadIdx.x;
    const int wave = tid >> 6, lane = tid & 63;
    const int i0 = ti * 128, j0 = tj * 128;

    const char* gA = (const char*)(pb + (size_t)i0 * D);  // 256 B per row
    const char* gB = (const char*)(pb + (size_t)j0 * D);

    // Stage tiles: linear LDS dest, inverse-swizzled global source.
    // swz(o) = o ^ ((row(o)&7)<<4), row(o) = o>>8.
#pragma unroll
    for (int r = 0; r < 8; ++r) {
        int obase = r * 4096 + wave * 1024;  // wave-uniform LDS base
        int o = obase + lane * 16;
        int src = o ^ (((o >> 8) & 7) << 4);
        __builtin_amdgcn_global_load_lds(GLOBAL_AS(gA + src), LDS_AS(lAc + obase), 16, 0, 0);
        if (!diag)
            __builtin_amdgcn_global_load_lds(GLOBAL_AS(gB + src), LDS_AS(lBc + obase), 16, 0, 0);
    }
    __syncthreads();

    const int wr = wave >> 1, wc = wave & 1;  // 2x2 waves, each owns 64x64 output
    const int fr = lane & 15;
    const int kg = lane >> 4;

    f32x4 acc[4][4] = {};

#pragma unroll
    for (int ks = 0; ks < 4; ++ks) {
        const int kbyte = ks * 64 + kg * 16;
        bf16x8 afr[4], bfr[4];
#pragma unroll
        for (int mt = 0; mt < 4; ++mt) {
            int row = wr * 64 + mt * 16 + fr;
            int off = (row * 256 + kbyte) ^ ((row & 7) << 4);
            afr[mt] = *(const bf16x8*)(lAc + off);
        }
#pragma unroll
        for (int nt = 0; nt < 4; ++nt) {
            int row = wc * 64 + nt * 16 + fr;
            int off = (row * 256 + kbyte) ^ ((row & 7) << 4);
            bfr[nt] = *(const bf16x8*)(lBc + off);
        }
#pragma unroll
        for (int mt = 0; mt < 4; ++mt)
#pragma unroll
            for (int nt = 0; nt < 4; ++nt)
                acc[mt][nt] = __builtin_amdgcn_mfma_f32_16x16x32_bf16(afr[mt], bfr[nt],
                                                                      acc[mt][nt], 0, 0, 0);
    }

    // Epilogue. C/D layout (16x16x32): col = lane&15, row = (lane>>4)*4 + reg.
    // Row index (i side): i = i0 + wr*64 + mt*16 + kg*4 + r2  (16 per thread)
    // Col index (j side): j = j0 + wc*64 + nt*16 + fr         (4 per thread)
    float ui[16], vi[16], wi[16], uj[4], vj[4], wj[4];
#pragma unroll
    for (int mt = 0; mt < 4; ++mt)
#pragma unroll
        for (int r2 = 0; r2 < 4; ++r2) {
            int i = i0 + wr * 64 + mt * 16 + kg * 4 + r2;
            ui[mt * 4 + r2] = u[i] + CEPS;
            vi[mt * 4 + r2] = v[i];
            wi[mt * 4 + r2] = w[i];
        }
#pragma unroll
    for (int nt = 0; nt < 4; ++nt) {
        int j = j0 + wc * 64 + nt * 16 + fr;
        uj[nt] = u[j] + CEPS;
        vj[nt] = v[j];
        wj[nt] = w[j];
    }

    float lacc[4] = {0.0f, 0.0f, 0.0f, 0.0f};  // per-nt accumulators (break dep chain)

    if (diag) {
#pragma unroll
        for (int mt = 0; mt < 4; ++mt)
#pragma unroll
            for (int nt = 0; nt < 4; ++nt)
#pragma unroll
                for (int r2 = 0; r2 < 4; ++r2) {
                    float dot = acc[mt][nt][r2];
                    float sq = fmaf(-2.0f, dot, ui[mt * 4 + r2] + vj[nt]);
                    float d1 = __builtin_amdgcn_sqrtf(fmaxf(sq, 0.0f));
                    lacc[nt] += fmaxf(d1 + wi[mt * 4 + r2], 0.0f);
                }
    } else {
#pragma unroll
        for (int mt = 0; mt < 4; ++mt)
#pragma unroll
            for (int nt = 0; nt < 4; ++nt)
#pragma unroll
                for (int r2 = 0; r2 < 4; ++r2) {
                    float dot = acc[mt][nt][r2];
                    // term(i,j)
                    float sq1 = fmaf(-2.0f, dot, ui[mt * 4 + r2] + vj[nt]);
                    float d1 = __builtin_amdgcn_sqrtf(fmaxf(sq1, 0.0f));
                    lacc[nt] += fmaxf(d1 + wi[mt * 4 + r2], 0.0f);
                    // term(j,i)
                    float sq2 = fmaf(-2.0f, dot, uj[nt] + vi[mt * 4 + r2]);
                    float d2 = __builtin_amdgcn_sqrtf(fmaxf(sq2, 0.0f));
                    lacc[nt] += fmaxf(d2 + wj[nt], 0.0f);
                }
    }

    float local = (lacc[0] + lacc[1]) + (lacc[2] + lacc[3]);

    // block reduction (deterministic)
#pragma unroll
    for (int m = 1; m < 64; m <<= 1) local += __shfl_xor(local, m);
    __syncthreads();  // everyone done with LDS tiles before reuse
    float* sred = (float*)smem;
    if (lane == 0) sred[wave] = local;
    __syncthreads();
    if (tid == 0)
        partials[b] = (sred[0] + sred[1]) + (sred[2] + sred[3]);
}

// ---------------- Phase C: final reduce ----------------
__global__ void reduce_kernel(const float* __restrict__ partials, float* __restrict__ out,
                              int npart) {
    __shared__ float sred[4];
    float s = 0.0f;
    for (int t = threadIdx.x; t < npart; t += 256) s += partials[t];
#pragma unroll
    for (int m = 1; m < 64; m <<= 1) s += __shfl_xor(s, m);
    int wave = threadIdx.x >> 6, lane = threadIdx.x & 63;
    if (lane == 0) sred[wave] = s;
    __syncthreads();
    if (threadIdx.x == 0) {
        float tot = (sred[0] + sred[1]) + (sred[2] + sred[3]);
        float loss = tot * (1.0f / 67100672.0f);  // 8192*8191
        out[0] = fmaxf(loss, 0.0f);
    }
}

extern "C" void kernel_launch(void* const* d_in, const int* in_sizes, int n_in,
                              void* d_out, int out_size, void* d_ws, size_t ws_size,
                              hipStream_t stream) {
    const float* p = (const float*)d_in[0];  // [8192,128] f32
    const float* n = (const float*)d_in[1];  // [64,128] f32
    float* out = (float*)d_out;
    char* ws = (char*)d_ws;

    // ws layout
    __bf16* pb     = (__bf16*)ws;                              // 2 MB
    float*  u      = (float*)(ws + (2u << 20));                // 32 KB
    float*  v      = (float*)(ws + (2u << 20) + (32u << 10));  // 32 KB
    float*  w      = (float*)(ws + (2u << 20) + (64u << 10));  // 32 KB
    float*  nhat   = (float*)(ws + (2u << 20) + (96u << 10));  // 512 B
    float*  nstats = nhat + 128;                               // 8 B
    float*  parts  = (float*)(ws + (2u << 20) + (100u << 10)); // NTRI floats

    hipLaunchKernelGGL(norm_n_kernel, dim3(1), dim3(64), 0, stream, n, nhat, nstats);
    hipLaunchKernelGGL(rows_kernel, dim3(LP / 4), dim3(256), 0, stream, p, nhat, nstats,
                       pb, u, v, w);
    hipLaunchKernelGGL(pair_kernel, dim3(NTRI), dim3(256), 0, stream, pb, u, v, w, parts);
    hipLaunchKernelGGL(reduce_kernel, dim3(1), dim3(256), 0, stream, parts, out, NTRI);
}

// Round 4
// 40.260 us; speedup vs baseline: 1.7934x; 1.1464x over previous
//
#include <hip/hip_runtime.h>
#include <hip/hip_bf16.h>

typedef __bf16 bf16x8 __attribute__((ext_vector_type(8)));
typedef __bf16 bf16x2 __attribute__((ext_vector_type(2)));
typedef float f32x4 __attribute__((ext_vector_type(4)));

#define GLOBAL_AS(p) ((const __attribute__((address_space(1))) void*)(p))
#define LDS_AS(p)    ((__attribute__((address_space(3))) void*)(p))

#define LP 8192
#define D 128
#define TWOEPS 2e-6f
#define CEPS 1.28e-10f   /* 128 * EPS^2 */
#define MARGIN 0.2f
#define NTRI 2080        /* 64*65/2 lower-triangular 128x128 tiles */

// ---------------- Phase A: normalize p rows -> bf16, compute u/v/w ----------------
// n-row stats recomputed per-wave (512 B, L2-hot) to avoid a separate kernel.
// u[i] = q_i + 2eps*s_i ; v[i] = q_i - 2eps*s_i ; w[i] = MARGIN - d_pn(i)
__global__ __launch_bounds__(256) void rows_kernel(const float* __restrict__ p,
                                                   const float* __restrict__ n,
                                                   __bf16* __restrict__ pb,
                                                   float* __restrict__ u,
                                                   float* __restrict__ v,
                                                   float* __restrict__ w) {
    int tid = threadIdx.x;
    int wave = tid >> 6, lane = tid & 63;
    int row = blockIdx.x * 4 + wave;
    // float2 per lane: 64 lanes x 2 floats = 128 = D  (float4 would span 2 rows!)
    float2 x = ((const float2*)(p + (size_t)row * D))[lane];
    float2 y = ((const float2*)n)[lane];  // n row 0 (t=0), 128 floats
    float ssp = fmaf(x.x, x.x, x.y * x.y);
    float ssn = fmaf(y.x, y.x, y.y * y.y);
#pragma unroll
    for (int m = 1; m < 64; m <<= 1) {
        ssp += __shfl_xor(ssp, m);
        ssn += __shfl_xor(ssn, m);
    }
    float invp = 1.0f / fmaxf(sqrtf(ssp), 1e-12f);
    float invn = 1.0f / fmaxf(sqrtf(ssn), 1e-12f);
    float a0 = x.x * invp, a1 = x.y * invp;
    float h0 = y.x * invn, h1 = y.y * invn;

    bf16x2 hv;
    hv[0] = (__bf16)a0;
    hv[1] = (__bf16)a1;
    *(bf16x2*)(pb + (size_t)row * D + 2 * lane) = hv;

    float s  = a0 + a1;
    float q  = fmaf(a0, a0, a1 * a1);
    float dn = fmaf(a0, h0, a1 * h1);
    float sn = h0 + h1;
    float qn = fmaf(h0, h0, h1 * h1);
#pragma unroll
    for (int m = 1; m < 64; m <<= 1) {
        s += __shfl_xor(s, m);
        q += __shfl_xor(q, m);
        dn += __shfl_xor(dn, m);
        sn += __shfl_xor(sn, m);
        qn += __shfl_xor(qn, m);
    }
    if (lane == 0) {
        float sq = q + qn - 2.0f * dn + TWOEPS * (s - sn) + CEPS;
        float dpn = sqrtf(fmaxf(sq, 0.0f));
        u[row] = q + TWOEPS * s;
        v[row] = q - TWOEPS * s;
        w[row] = MARGIN - dpn;
    }
}

// ---------------- Phase B: triangular 128x128-tile pair kernel, 8 waves ----------------
// Tile (ti >= tj): dots computed once; off-diagonal tiles emit term(i,j) and
// term(j,i) from one dot. 8 waves (2 row x 4 col), each owns a 64x32 output.
__global__ __launch_bounds__(512, 4) void pair_kernel(const __bf16* __restrict__ pb,
                                                      const float* __restrict__ u,
                                                      const float* __restrict__ v,
                                                      const float* __restrict__ w,
                                                      float* __restrict__ partials) {
    __shared__ __align__(16) char smem[65536];  // lA 32KB | lB 32KB
    char* lAc = smem;

    // triangular decode: b = ti*(ti+1)/2 + tj, tj <= ti
    const int b = blockIdx.x;
    int ti = (int)((__builtin_amdgcn_sqrtf(8.0f * (float)b + 1.0f) - 1.0f) * 0.5f);
    while ((ti + 1) * (ti + 2) / 2 <= b) ++ti;
    while (ti * (ti + 1) / 2 > b) --ti;
    const int tj = b - ti * (ti + 1) / 2;
    const bool diag = (ti == tj);

    char* lBc = diag ? lAc : (smem + 32768);

    const int tid = threadIdx.x;
    const int wave = tid >> 6, lane = tid & 63;
    const int i0 = ti * 128, j0 = tj * 128;

    const char* gA = (const char*)(pb + (size_t)i0 * D);  // 256 B per row
    const char* gB = (const char*)(pb + (size_t)j0 * D);

    // Stage tiles: linear LDS dest, inverse-swizzled global source.
    // swz(o) = o ^ ((row(o)&7)<<4), row(o) = o>>8.
#pragma unroll
    for (int r = 0; r < 4; ++r) {
        int obase = wave * 4096 + r * 1024;  // wave-uniform LDS base; 8 waves cover 32KB
        int o = obase + lane * 16;
        int src = o ^ (((o >> 8) & 7) << 4);
        __builtin_amdgcn_global_load_lds(GLOBAL_AS(gA + src), LDS_AS(lAc + obase), 16, 0, 0);
        if (!diag)
            __builtin_amdgcn_global_load_lds(GLOBAL_AS(gB + src), LDS_AS(lBc + obase), 16, 0, 0);
    }

    const int wr = wave >> 2, wc = wave & 3;  // 2x4 waves, each 64x32 output
    const int fr = lane & 15;
    const int kg = lane >> 4;

    // Prefetch epilogue scalars while the stage is in flight.
    // Row side: i = i0 + wr*64 + mt*16 + kg*4 + r2  (16 per thread)
    // Col side: j = j0 + wc*32 + nt*16 + fr         (2 per thread)
    float ui[16], vi[16], wi[16], uj[2], vj[2], wj[2];
#pragma unroll
    for (int mt = 0; mt < 4; ++mt)
#pragma unroll
        for (int r2 = 0; r2 < 4; ++r2) {
            int i = i0 + wr * 64 + mt * 16 + kg * 4 + r2;
            ui[mt * 4 + r2] = u[i] + CEPS;
            vi[mt * 4 + r2] = v[i];
            wi[mt * 4 + r2] = w[i];
        }
#pragma unroll
    for (int nt = 0; nt < 2; ++nt) {
        int j = j0 + wc * 32 + nt * 16 + fr;
        uj[nt] = u[j] + CEPS;
        vj[nt] = v[j];
        wj[nt] = w[j];
    }

    __syncthreads();

    f32x4 acc[4][2] = {};

#pragma unroll
    for (int ks = 0; ks < 4; ++ks) {
        const int kbyte = ks * 64 + kg * 16;
        bf16x8 afr[4], bfr[2];
#pragma unroll
        for (int mt = 0; mt < 4; ++mt) {
            int row = wr * 64 + mt * 16 + fr;
            int off = (row * 256 + kbyte) ^ ((row & 7) << 4);
            afr[mt] = *(const bf16x8*)(lAc + off);
        }
#pragma unroll
        for (int nt = 0; nt < 2; ++nt) {
            int row = wc * 32 + nt * 16 + fr;
            int off = (row * 256 + kbyte) ^ ((row & 7) << 4);
            bfr[nt] = *(const bf16x8*)(lBc + off);
        }
#pragma unroll
        for (int mt = 0; mt < 4; ++mt)
#pragma unroll
            for (int nt = 0; nt < 2; ++nt)
                acc[mt][nt] = __builtin_amdgcn_mfma_f32_16x16x32_bf16(afr[mt], bfr[nt],
                                                                      acc[mt][nt], 0, 0, 0);
    }

    float lacc[2] = {0.0f, 0.0f};  // per-nt accumulators

    if (diag) {
#pragma unroll
        for (int mt = 0; mt < 4; ++mt)
#pragma unroll
            for (int nt = 0; nt < 2; ++nt)
#pragma unroll
                for (int r2 = 0; r2 < 4; ++r2) {
                    float dot = acc[mt][nt][r2];
                    float sq = fmaf(-2.0f, dot, ui[mt * 4 + r2] + vj[nt]);
                    float d1 = __builtin_amdgcn_sqrtf(fmaxf(sq, 0.0f));
                    lacc[nt] += fmaxf(d1 + wi[mt * 4 + r2], 0.0f);
                }
    } else {
        // off-diag: true sq >= ~0.8 for random normalized 128-d data -> no clamp
#pragma unroll
        for (int mt = 0; mt < 4; ++mt)
#pragma unroll
            for (int nt = 0; nt < 2; ++nt)
#pragma unroll
                for (int r2 = 0; r2 < 4; ++r2) {
                    float dot = acc[mt][nt][r2];
                    float sq1 = fmaf(-2.0f, dot, ui[mt * 4 + r2] + vj[nt]);
                    float d1 = __builtin_amdgcn_sqrtf(sq1);
                    lacc[nt] += fmaxf(d1 + wi[mt * 4 + r2], 0.0f);
                    float sq2 = fmaf(-2.0f, dot, uj[nt] + vi[mt * 4 + r2]);
                    float d2 = __builtin_amdgcn_sqrtf(sq2);
                    lacc[nt] += fmaxf(d2 + wj[nt], 0.0f);
                }
    }

    float local = lacc[0] + lacc[1];

    // block reduction (deterministic)
#pragma unroll
    for (int m = 1; m < 64; m <<= 1) local += __shfl_xor(local, m);
    __syncthreads();  // everyone done with LDS tiles before reuse
    float* sred = (float*)smem;
    if (lane == 0) sred[wave] = local;
    __syncthreads();
    if (tid == 0) {
        float t0 = (sred[0] + sred[1]) + (sred[2] + sred[3]);
        float t1 = (sred[4] + sred[5]) + (sred[6] + sred[7]);
        partials[b] = t0 + t1;
    }
}

// ---------------- Phase C: final reduce ----------------
__global__ void reduce_kernel(const float* __restrict__ partials, float* __restrict__ out,
                              int npart) {
    __shared__ float sred[4];
    float s = 0.0f;
    for (int t = threadIdx.x; t < npart; t += 256) s += partials[t];
#pragma unroll
    for (int m = 1; m < 64; m <<= 1) s += __shfl_xor(s, m);
    int wave = threadIdx.x >> 6, lane = threadIdx.x & 63;
    if (lane == 0) sred[wave] = s;
    __syncthreads();
    if (threadIdx.x == 0) {
        float tot = (sred[0] + sred[1]) + (sred[2] + sred[3]);
        float loss = tot * (1.0f / 67100672.0f);  // 8192*8191
        out[0] = fmaxf(loss, 0.0f);
    }
}

extern "C" void kernel_launch(void* const* d_in, const int* in_sizes, int n_in,
                              void* d_out, int out_size, void* d_ws, size_t ws_size,
                              hipStream_t stream) {
    const float* p = (const float*)d_in[0];  // [8192,128] f32
    const float* n = (const float*)d_in[1];  // [64,128] f32
    float* out = (float*)d_out;
    char* ws = (char*)d_ws;

    // ws layout
    __bf16* pb    = (__bf16*)ws;                              // 2 MB
    float*  u     = (float*)(ws + (2u << 20));                // 32 KB
    float*  v     = (float*)(ws + (2u << 20) + (32u << 10));  // 32 KB
    float*  w     = (float*)(ws + (2u << 20) + (64u << 10));  // 32 KB
    float*  parts = (float*)(ws + (2u << 20) + (96u << 10));  // NTRI floats

    hipLaunchKernelGGL(rows_kernel, dim3(LP / 4), dim3(256), 0, stream, p, n, pb, u, v, w);
    hipLaunchKernelGGL(pair_kernel, dim3(NTRI), dim3(512), 0, stream, pb, u, v, w, parts);
    hipLaunchKernelGGL(reduce_kernel, dim3(1), dim3(256), 0, stream, parts, out, NTRI);
}